// Round 1
// baseline (844.101 us; speedup 1.0000x reference)
//
#include <hip/hip_runtime.h>

// Problem dims (fixed by reference)
constexpr int Bb    = 8;
constexpr int Ntok  = 2048;
constexpr int Cdim  = 768;
constexpr int Ddim  = 384;
constexpr int Mrows = Bb * Ntok;  // 16384

// ---------------------------------------------------------------------------
// gemm_nt128: C[M,N] = A[M,K] * W[N,K]^T + bias[N]
// 128x128 tile, BK=16, 256 threads, 8x8 per thread. All dims multiples assumed.
// ---------------------------------------------------------------------------
__global__ __launch_bounds__(256) void gemm_nt128(const float* __restrict__ A,
                                                  const float* __restrict__ W,
                                                  const float* __restrict__ bias,
                                                  float* __restrict__ C,
                                                  int M, int N, int K) {
    __shared__ float As[16][132];
    __shared__ float Bs[16][132];
    const int bm = blockIdx.y * 128;
    const int bn = blockIdx.x * 128;
    const int tid = threadIdx.x;
    const int lk = tid & 15;   // k within tile for loads
    const int lm = tid >> 4;   // row base for loads
    const int tx = tid & 15;   // col group for compute
    const int ty = tid >> 4;   // row group for compute
    float acc[8][8] = {};
    for (int k0 = 0; k0 < K; k0 += 16) {
#pragma unroll
        for (int r = 0; r < 8; ++r) {
            As[lk][lm + r * 16] = A[(size_t)(bm + lm + r * 16) * K + (k0 + lk)];
            Bs[lk][lm + r * 16] = W[(size_t)(bn + lm + r * 16) * K + (k0 + lk)];
        }
        __syncthreads();
#pragma unroll
        for (int k = 0; k < 16; ++k) {
            float a0[8], b0[8];
#pragma unroll
            for (int i = 0; i < 8; ++i) a0[i] = As[k][ty * 8 + i];
#pragma unroll
            for (int j = 0; j < 8; ++j) b0[j] = Bs[k][tx * 8 + j];
#pragma unroll
            for (int i = 0; i < 8; ++i)
#pragma unroll
                for (int j = 0; j < 8; ++j)
                    acc[i][j] = fmaf(a0[i], b0[j], acc[i][j]);
        }
        __syncthreads();
    }
#pragma unroll
    for (int i = 0; i < 8; ++i) {
        const size_t row = (size_t)(bm + ty * 8 + i);
#pragma unroll
        for (int j = 0; j < 8; ++j) {
            const int col = bn + tx * 8 + j;
            C[row * N + col] = acc[i][j] + bias[col];
        }
    }
}

// ---------------------------------------------------------------------------
// gemm_tn64: per-batch M_b[d1][d2] = (sum_n phi[b,n,d1] * g[b,n,d2]) / Ntok
// A,B are [Ntok][Ddim] per batch (K-major) -> fully coalesced 64-wide loads.
// 64x64 tile, BK=16, 4x4 per thread.
// ---------------------------------------------------------------------------
__global__ __launch_bounds__(256) void gemm_tn64(const float* __restrict__ phi,
                                                 const float* __restrict__ g,
                                                 float* __restrict__ Mout) {
    const int b = blockIdx.z;
    const float* A  = phi + (size_t)b * Ntok * Ddim;
    const float* Bp = g   + (size_t)b * Ntok * Ddim;
    float* Cm = Mout + (size_t)b * Ddim * Ddim;
    const int bm = blockIdx.y * 64;
    const int bn = blockIdx.x * 64;
    __shared__ float As[16][68];
    __shared__ float Bs[16][68];
    const int tid = threadIdx.x;
    const int lm = tid & 63;
    const int lk4 = tid >> 6;
    const int tx = tid & 15, ty = tid >> 4;
    float acc[4][4] = {};
    for (int n0 = 0; n0 < Ntok; n0 += 16) {
#pragma unroll
        for (int r = 0; r < 4; ++r) {
            As[lk4 + r * 4][lm] = A[(size_t)(n0 + lk4 + r * 4) * Ddim + bm + lm];
            Bs[lk4 + r * 4][lm] = Bp[(size_t)(n0 + lk4 + r * 4) * Ddim + bn + lm];
        }
        __syncthreads();
#pragma unroll
        for (int k = 0; k < 16; ++k) {
            float a0[4], b0[4];
#pragma unroll
            for (int i = 0; i < 4; ++i) a0[i] = As[k][ty * 4 + i];
#pragma unroll
            for (int j = 0; j < 4; ++j) b0[j] = Bs[k][tx * 4 + j];
#pragma unroll
            for (int i = 0; i < 4; ++i)
#pragma unroll
                for (int j = 0; j < 4; ++j)
                    acc[i][j] = fmaf(a0[i], b0[j], acc[i][j]);
        }
        __syncthreads();
    }
    constexpr float scale = 1.0f / (float)Ntok;
#pragma unroll
    for (int i = 0; i < 4; ++i)
#pragma unroll
        for (int j = 0; j < 4; ++j)
            Cm[(size_t)(bm + ty * 4 + i) * Ddim + bn + tx * 4 + j] = acc[i][j] * scale;
}

// ---------------------------------------------------------------------------
// gemm_nn64: per-batch Y[n][d2] = sum_d1 theta[b,n,d1] * M_b[d1][d2]
// 64x64 tile, BK=16, 4x4 per thread.
// ---------------------------------------------------------------------------
__global__ __launch_bounds__(256) void gemm_nn64(const float* __restrict__ theta,
                                                 const float* __restrict__ Mall,
                                                 float* __restrict__ Y) {
    const int b = blockIdx.z;
    const float* A  = theta + (size_t)b * Ntok * Ddim;
    const float* Bm = Mall  + (size_t)b * Ddim * Ddim;
    float* C = Y + (size_t)b * Ntok * Ddim;
    const int bm = blockIdx.y * 64;
    const int bn = blockIdx.x * 64;
    __shared__ float As[16][68];
    __shared__ float Bs[16][68];
    const int tid = threadIdx.x;
    const int lk = tid & 15, lmr = tid >> 4;
    const int lm = tid & 63, lk4 = tid >> 6;
    const int tx = tid & 15, ty = tid >> 4;
    float acc[4][4] = {};
    for (int k0 = 0; k0 < Ddim; k0 += 16) {
#pragma unroll
        for (int r = 0; r < 4; ++r) {
            As[lk][lmr + r * 16]  = A[(size_t)(bm + lmr + r * 16) * Ddim + k0 + lk];
            Bs[lk4 + r * 4][lm]   = Bm[(size_t)(k0 + lk4 + r * 4) * Ddim + bn + lm];
        }
        __syncthreads();
#pragma unroll
        for (int k = 0; k < 16; ++k) {
            float a0[4], b0[4];
#pragma unroll
            for (int i = 0; i < 4; ++i) a0[i] = As[k][ty * 4 + i];
#pragma unroll
            for (int j = 0; j < 4; ++j) b0[j] = Bs[k][tx * 4 + j];
#pragma unroll
            for (int i = 0; i < 4; ++i)
#pragma unroll
                for (int j = 0; j < 4; ++j)
                    acc[i][j] = fmaf(a0[i], b0[j], acc[i][j]);
        }
        __syncthreads();
    }
#pragma unroll
    for (int i = 0; i < 4; ++i)
#pragma unroll
        for (int j = 0; j < 4; ++j)
            C[(size_t)(bm + ty * 4 + i) * Ddim + bn + tx * 4 + j] = acc[i][j];
}

// ---------------------------------------------------------------------------
// BN stats, deterministic two-stage column reduction over [16384][768]
// ---------------------------------------------------------------------------
__global__ __launch_bounds__(256) void bn_partial(const float* __restrict__ y,
                                                  float* __restrict__ psum,
                                                  float* __restrict__ psq) {
    const int tid = threadIdx.x;
    const size_t row0 = (size_t)blockIdx.x * 64;
    float s0 = 0, s1 = 0, s2 = 0, q0 = 0, q1 = 0, q2 = 0;
    for (int r = 0; r < 64; ++r) {
        const float* rp = y + (row0 + r) * Cdim;
        const float v0 = rp[tid];
        const float v1 = rp[tid + 256];
        const float v2 = rp[tid + 512];
        s0 += v0; q0 = fmaf(v0, v0, q0);
        s1 += v1; q1 = fmaf(v1, v1, q1);
        s2 += v2; q2 = fmaf(v2, v2, q2);
    }
    const size_t o = (size_t)blockIdx.x * Cdim;
    psum[o + tid] = s0; psum[o + tid + 256] = s1; psum[o + tid + 512] = s2;
    psq[o + tid]  = q0; psq[o + tid + 256]  = q1; psq[o + tid + 512]  = q2;
}

__global__ __launch_bounds__(256) void bn_finalize(const float* __restrict__ psum,
                                                   const float* __restrict__ psq,
                                                   const float* __restrict__ gamma,
                                                   const float* __restrict__ beta,
                                                   float* __restrict__ a,
                                                   float* __restrict__ bb) {
    const int c = blockIdx.x * 256 + threadIdx.x;
    if (c >= Cdim) return;
    float s = 0.f, q = 0.f;
    for (int b = 0; b < 256; ++b) { s += psum[(size_t)b * Cdim + c]; q += psq[(size_t)b * Cdim + c]; }
    const float mean = s * (1.0f / (float)Mrows);
    const float var  = fmaf(-mean, mean, q * (1.0f / (float)Mrows));
    const float inv  = rsqrtf(var + 1e-5f);
    const float gsc  = gamma[c] * inv;
    a[c]  = gsc;
    bb[c] = fmaf(-mean, gsc, beta[c]);
}

// out = a[c]*y + bb[c] + x_h   (in place on y == out), float4 path
__global__ __launch_bounds__(256) void bn_apply(const float* __restrict__ y,
                                                const float* __restrict__ xh,
                                                const float* __restrict__ a,
                                                const float* __restrict__ bb,
                                                float* __restrict__ outp) {
    const size_t i = (size_t)blockIdx.x * 256 + threadIdx.x;  // float4 index
    const float4 v = ((const float4*)y)[i];
    const float4 x = ((const float4*)xh)[i];
    const int c4 = (int)(i % (Cdim / 4));
    const float4 A  = ((const float4*)a)[c4];
    const float4 Bv = ((const float4*)bb)[c4];
    float4 o;
    o.x = fmaf(A.x, v.x, Bv.x) + x.x;
    o.y = fmaf(A.y, v.y, Bv.y) + x.y;
    o.z = fmaf(A.z, v.z, Bv.z) + x.z;
    o.w = fmaf(A.w, v.w, Bv.w) + x.w;
    ((float4*)outp)[i] = o;
}

// ---------------------------------------------------------------------------
extern "C" void kernel_launch(void* const* d_in, const int* in_sizes, int n_in,
                              void* d_out, int out_size, void* d_ws, size_t ws_size,
                              hipStream_t stream) {
    const float* x_h   = (const float*)d_in[0];
    const float* x_l   = (const float*)d_in[1];
    const float* w_g   = (const float*)d_in[2];
    const float* b_g   = (const float*)d_in[3];
    const float* w_th  = (const float*)d_in[4];
    const float* b_th  = (const float*)d_in[5];
    const float* w_ph  = (const float*)d_in[6];
    const float* b_ph  = (const float*)d_in[7];
    const float* w_out = (const float*)d_in[8];
    const float* b_out = (const float*)d_in[9];
    const float* gamma = (const float*)d_in[10];
    const float* beta  = (const float*)d_in[11];
    float* out = (float*)d_out;

    // workspace layout (floats): total 20,448,768 floats = 81.8 MB
    float* ws   = (float*)d_ws;
    float* Pbuf = ws;                                  // phi, then y1: 16384*384
    float* Mbuf = Pbuf + (size_t)Mrows * Ddim;         // 8*384*384
    float* psum = Mbuf + (size_t)Bb * Ddim * Ddim;     // 256*768
    float* psq  = psum + (size_t)256 * Cdim;           // 256*768
    float* avec = psq  + (size_t)256 * Cdim;           // 768
    float* bvec = avec + Cdim;                         // 768
    float* Tbuf = bvec + Cdim;                         // theta: 16384*384
    float* Gbuf = Tbuf + (size_t)Mrows * Ddim;         // g:     16384*384

    dim3 blk(256);

    // theta = x_h * w_theta^T + b_theta
    gemm_nt128<<<dim3(Ddim / 128, Mrows / 128), blk, 0, stream>>>(
        x_h, w_th, b_th, Tbuf, Mrows, Ddim, Cdim);
    // phi = x_l * w_phi^T + b_phi
    gemm_nt128<<<dim3(Ddim / 128, Mrows / 128), blk, 0, stream>>>(
        x_l, w_ph, b_ph, Pbuf, Mrows, Ddim, Cdim);
    // g = x_l * w_g^T + b_g
    gemm_nt128<<<dim3(Ddim / 128, Mrows / 128), blk, 0, stream>>>(
        x_l, w_g, b_g, Gbuf, Mrows, Ddim, Cdim);
    // M_b = phi_b^T * g_b / Ntok   (associativity rewrite: kills the N^2 attention)
    gemm_tn64<<<dim3(Ddim / 64, Ddim / 64, Bb), blk, 0, stream>>>(Pbuf, Gbuf, Mbuf);
    // y1 = theta * M_b  (overwrites phi buffer)
    gemm_nn64<<<dim3(Ddim / 64, Ntok / 64, Bb), blk, 0, stream>>>(Tbuf, Mbuf, Pbuf);
    // y = y1 * w_out^T + b_out  -> d_out (pre-BN)
    gemm_nt128<<<dim3(Cdim / 128, Mrows / 128), blk, 0, stream>>>(
        Pbuf, w_out, b_out, out, Mrows, Cdim, Ddim);
    // BN stats (deterministic 2-stage), then normalize + residual in place
    bn_partial<<<dim3(Mrows / 64), blk, 0, stream>>>(out, psum, psq);
    bn_finalize<<<dim3(3), blk, 0, stream>>>(psum, psq, gamma, beta, avec, bvec);
    bn_apply<<<dim3((size_t)Mrows * Cdim / 4 / 256), blk, 0, stream>>>(
        out, x_h, avec, bvec, out);
}

// Round 4
// 239.047 us; speedup vs baseline: 3.5311x; 3.5311x over previous
//
#include <hip/hip_runtime.h>
#include <hip/hip_bf16.h>

typedef short bf16x8 __attribute__((ext_vector_type(8)));
typedef float f32x4 __attribute__((ext_vector_type(4)));

constexpr int Bb = 8, Ntok = 2048, Cdim = 768, Ddim = 384, Mrows = 16384;

__device__ __forceinline__ void gload16(const void* g, void* l) {
    __builtin_amdgcn_global_load_lds(
        (const __attribute__((address_space(1))) unsigned int*)g,
        (__attribute__((address_space(3))) unsigned int*)l, 16, 0, 0);
}

// Hand-rolled RNE fp32->bf16 (finite inputs only)
__device__ __forceinline__ unsigned short f2bf(float x) {
    union { float f; unsigned u; } c; c.f = x;
    const unsigned r = c.u + 0x7fffu + ((c.u >> 16) & 1u);
    return (unsigned short)(r >> 16);
}

// ---------------------------------------------------------------------------
// fp32 -> bf16 casts
// ---------------------------------------------------------------------------
__global__ __launch_bounds__(256) void cast_x(const float* __restrict__ s,
                                              unsigned short* __restrict__ d, int n8) {
    const int i = blockIdx.x * 256 + threadIdx.x;
    if (i >= n8) return;
    const float4* s4 = (const float4*)s;
    const float4 a = s4[2 * i], b = s4[2 * i + 1];
    union { unsigned short u[8]; uint4 q; } r;
    r.u[0] = f2bf(a.x); r.u[1] = f2bf(a.y); r.u[2] = f2bf(a.z); r.u[3] = f2bf(a.w);
    r.u[4] = f2bf(b.x); r.u[5] = f2bf(b.y); r.u[6] = f2bf(b.z); r.u[7] = f2bf(b.w);
    ((uint4*)d)[i] = r.q;
}

__global__ __launch_bounds__(256) void cast_w(const float* __restrict__ s0, const float* __restrict__ s1,
                                              const float* __restrict__ s2, const float* __restrict__ s3,
                                              unsigned short* __restrict__ d0, unsigned short* __restrict__ d1,
                                              unsigned short* __restrict__ d2, unsigned short* __restrict__ d3) {
    constexpr int n8 = 294912 / 8;  // 36864 uint4-chunks per weight
    const int i = blockIdx.x * 256 + threadIdx.x;  // 0..147455
    const int sel = i / n8, loc = i - sel * n8;
    const float* s = sel == 0 ? s0 : sel == 1 ? s1 : sel == 2 ? s2 : s3;
    unsigned short* d = sel == 0 ? d0 : sel == 1 ? d1 : sel == 2 ? d2 : d3;
    const float4* s4 = (const float4*)s;
    const float4 a = s4[2 * loc], b = s4[2 * loc + 1];
    union { unsigned short u[8]; uint4 q; } r;
    r.u[0] = f2bf(a.x); r.u[1] = f2bf(a.y); r.u[2] = f2bf(a.z); r.u[3] = f2bf(a.w);
    r.u[4] = f2bf(b.x); r.u[5] = f2bf(b.y); r.u[6] = f2bf(b.z); r.u[7] = f2bf(b.w);
    ((uint4*)d)[loc] = r.q;  // FIXED: was [i] — wrote sel*36864 u4 past the buffer start
}

// ---------------------------------------------------------------------------
// bf16 MFMA NT GEMM: C = A[M,K] * B[N,K]^T (+bias) ; 128x128 tile, BK=32,
// 4 waves (2x2), 64x64 per wave, mfma_f32_16x16x32_bf16, global_load_lds w16.
// OMODE 0: fp32 out [M][N] + bias
// OMODE 1: bf16 out [M][N], optional bias, scale
// OMODE 2: bf16 out TRANSPOSED per batch: out[b][col][token] (+bias) via LDS
//          transpose buffer (batch derived from global row, Ntok=2048)
// ---------------------------------------------------------------------------
template <int OMODE>
__global__ __launch_bounds__(256) void gemm_bf16(
        const unsigned short* __restrict__ Abase, long sA,
        const unsigned short* __restrict__ Bbase, long sB,
        const float* __restrict__ bias,
        void* __restrict__ Cbase, long sC,
        int M, int N, int K, float scale) {
    constexpr int SMEM_BYTES = (OMODE == 2) ? 34304 : 16384;
    __shared__ __align__(16) char smem[SMEM_BYTES];
    char* smA = smem;
    char* smB = smem + 8192;

    const int tid  = threadIdx.x;
    const int lane = tid & 63;
    const int w    = tid >> 6;
    const int wm   = w >> 1, wn = w & 1;
    const int bm = blockIdx.y * 128, bn = blockIdx.x * 128;
    const int z  = blockIdx.z;

    const unsigned short* A = Abase + (size_t)z * sA;
    const unsigned short* B = Bbase + (size_t)z * sB;

    // staging map: thread t covers 16B = 8 bf16 at tile (row=t>>2 (+64), k=(t&3)*8)
    const int ldRow = tid >> 2;
    const int ldK   = (tid & 3) * 8;
    const unsigned ldsOff = tid * 16;
    const size_t aOff0 = (size_t)(bm + ldRow) * K + ldK;
    const size_t aOff1 = (size_t)(bm + 64 + ldRow) * K + ldK;
    const size_t bOff0 = (size_t)(bn + ldRow) * K + ldK;
    const size_t bOff1 = (size_t)(bn + 64 + ldRow) * K + ldK;

    f32x4 acc[4][4] = {};

    const int fr = lane & 15;          // fragment row/col within 16
    const int fh = (lane >> 4) * 16;   // byte offset of k-octet

    for (int k0 = 0; k0 < K; k0 += 32) {
        gload16(A + aOff0 + k0, smA + ldsOff);
        gload16(A + aOff1 + k0, smA + 4096 + ldsOff);
        gload16(B + bOff0 + k0, smB + ldsOff);
        gload16(B + bOff1 + k0, smB + 4096 + ldsOff);
        asm volatile("s_waitcnt vmcnt(0)" ::: "memory");
        __syncthreads();
        bf16x8 fa[4], fb[4];
#pragma unroll
        for (int m = 0; m < 4; ++m)
            fa[m] = *(const bf16x8*)(smA + (wm * 64 + m * 16 + fr) * 64 + fh);
#pragma unroll
        for (int n = 0; n < 4; ++n)
            fb[n] = *(const bf16x8*)(smB + (wn * 64 + n * 16 + fr) * 64 + fh);
#pragma unroll
        for (int m = 0; m < 4; ++m)
#pragma unroll
            for (int n = 0; n < 4; ++n)
                acc[m][n] = __builtin_amdgcn_mfma_f32_16x16x32_bf16(fa[m], fb[n], acc[m][n], 0, 0, 0);
        __syncthreads();
    }

    const int r0 = (lane >> 4) * 4;
    const int cc = lane & 15;

    if constexpr (OMODE == 0) {
        float* C = (float*)Cbase + (size_t)z * sC;
#pragma unroll
        for (int n = 0; n < 4; ++n) {
            const int col = bn + wn * 64 + n * 16 + cc;
            const float bv = bias[col];
#pragma unroll
            for (int m = 0; m < 4; ++m)
#pragma unroll
                for (int j = 0; j < 4; ++j)
                    C[(size_t)(bm + wm * 64 + m * 16 + r0 + j) * N + col] = acc[m][n][j] + bv;
        }
    } else if constexpr (OMODE == 1) {
        unsigned short* C = (unsigned short*)Cbase + (size_t)z * sC;
#pragma unroll
        for (int n = 0; n < 4; ++n) {
            const int col = bn + wn * 64 + n * 16 + cc;
            const float bv = bias ? bias[col] : 0.0f;
#pragma unroll
            for (int m = 0; m < 4; ++m)
#pragma unroll
                for (int j = 0; j < 4; ++j)
                    C[(size_t)(bm + wm * 64 + m * 16 + r0 + j) * N + col] =
                        f2bf(acc[m][n][j] * scale + bv);
        }
    } else {
        // OMODE 2: LDS transpose then coalesced store to [b][col][token]
        unsigned short* T = (unsigned short*)smem;  // [128 cols][134 rows] bf16 (pad 134)
#pragma unroll
        for (int n = 0; n < 4; ++n) {
            const int ccol = wn * 64 + n * 16 + cc;
            const float bv = bias[bn + ccol];
#pragma unroll
            for (int m = 0; m < 4; ++m)
#pragma unroll
                for (int j = 0; j < 4; ++j)
                    T[ccol * 134 + (wm * 64 + m * 16 + r0 + j)] = f2bf(acc[m][n][j] + bv);
        }
        __syncthreads();
        const int b   = bm >> 11;     // bm / 2048 (Ntok = 2048)
        const int bmb = bm & 2047;
        unsigned short* Co = (unsigned short*)Cbase + (size_t)b * N * Ntok;
#pragma unroll
        for (int i = 0; i < 32; ++i) {
            const int d = w * 32 + i;  // column of tile, uniform per wave
            const unsigned v = *(const unsigned*)((const char*)smem + d * 268 + lane * 4);
            *(unsigned*)(Co + (size_t)(bn + d) * Ntok + bmb + lane * 2) = v;
        }
    }
}

// ---------------------------------------------------------------------------
// BN stats, deterministic two-stage column reduction over [16384][768]
// ---------------------------------------------------------------------------
__global__ __launch_bounds__(256) void bn_partial(const float* __restrict__ y,
                                                  float* __restrict__ psum,
                                                  float* __restrict__ psq) {
    const int tid = threadIdx.x;
    const size_t row0 = (size_t)blockIdx.x * 64;
    float s0 = 0, s1 = 0, s2 = 0, q0 = 0, q1 = 0, q2 = 0;
    for (int r = 0; r < 64; ++r) {
        const float* rp = y + (row0 + r) * Cdim;
        const float v0 = rp[tid];
        const float v1 = rp[tid + 256];
        const float v2 = rp[tid + 512];
        s0 += v0; q0 = fmaf(v0, v0, q0);
        s1 += v1; q1 = fmaf(v1, v1, q1);
        s2 += v2; q2 = fmaf(v2, v2, q2);
    }
    const size_t o = (size_t)blockIdx.x * Cdim;
    psum[o + tid] = s0; psum[o + tid + 256] = s1; psum[o + tid + 512] = s2;
    psq[o + tid]  = q0; psq[o + tid + 256]  = q1; psq[o + tid + 512]  = q2;
}

__global__ __launch_bounds__(256) void bn_finalize(const float* __restrict__ psum,
                                                   const float* __restrict__ psq,
                                                   const float* __restrict__ gamma,
                                                   const float* __restrict__ beta,
                                                   float* __restrict__ a,
                                                   float* __restrict__ bb) {
    const int c = blockIdx.x * 256 + threadIdx.x;
    if (c >= Cdim) return;
    float s = 0.f, q = 0.f;
    for (int b = 0; b < 256; ++b) { s += psum[(size_t)b * Cdim + c]; q += psq[(size_t)b * Cdim + c]; }
    const float mean = s * (1.0f / (float)Mrows);
    const float var  = fmaf(-mean, mean, q * (1.0f / (float)Mrows));
    const float inv  = rsqrtf(var + 1e-5f);
    const float gsc  = gamma[c] * inv;
    a[c]  = gsc;
    bb[c] = fmaf(-mean, gsc, beta[c]);
}

__global__ __launch_bounds__(256) void bn_apply(const float* __restrict__ y,
                                                const float* __restrict__ xh,
                                                const float* __restrict__ a,
                                                const float* __restrict__ bb,
                                                float* __restrict__ outp) {
    const size_t i = (size_t)blockIdx.x * 256 + threadIdx.x;  // float4 index
    const float4 v = ((const float4*)y)[i];
    const float4 x = ((const float4*)xh)[i];
    const int c4 = (int)(i % (Cdim / 4));
    const float4 A  = ((const float4*)a)[c4];
    const float4 Bv = ((const float4*)bb)[c4];
    float4 o;
    o.x = fmaf(A.x, v.x, Bv.x) + x.x;
    o.y = fmaf(A.y, v.y, Bv.y) + x.y;
    o.z = fmaf(A.z, v.z, Bv.z) + x.z;
    o.w = fmaf(A.w, v.w, Bv.w) + x.w;
    ((float4*)outp)[i] = o;
}

// ---------------------------------------------------------------------------
extern "C" void kernel_launch(void* const* d_in, const int* in_sizes, int n_in,
                              void* d_out, int out_size, void* d_ws, size_t ws_size,
                              hipStream_t stream) {
    const float* x_h   = (const float*)d_in[0];
    const float* x_l   = (const float*)d_in[1];
    const float* w_g   = (const float*)d_in[2];
    const float* b_g   = (const float*)d_in[3];
    const float* w_th  = (const float*)d_in[4];
    const float* b_th  = (const float*)d_in[5];
    const float* w_ph  = (const float*)d_in[6];
    const float* b_ph  = (const float*)d_in[7];
    const float* w_out = (const float*)d_in[8];
    const float* b_out = (const float*)d_in[9];
    const float* gamma = (const float*)d_in[10];
    const float* beta  = (const float*)d_in[11];
    float* out = (float*)d_out;

    // workspace layout (bytes, 16B aligned): total ~69.5 MB
    char* p = (char*)d_ws;
    unsigned short* Xbuf  = (unsigned short*)p; p += (size_t)Mrows * Cdim * 2;   // also Y1 later
    unsigned short* Wth16 = (unsigned short*)p; p += 294912 * 2;
    unsigned short* Wph16 = (unsigned short*)p; p += 294912 * 2;
    unsigned short* Wg16  = (unsigned short*)p; p += 294912 * 2;
    unsigned short* Wout16= (unsigned short*)p; p += 294912 * 2;
    unsigned short* Tbuf  = (unsigned short*)p; p += (size_t)Mrows * Ddim * 2;   // theta
    unsigned short* PhiT  = (unsigned short*)p; p += (size_t)Mrows * Ddim * 2;   // [b][384][2048]
    unsigned short* GT    = (unsigned short*)p; p += (size_t)Mrows * Ddim * 2;   // [b][384][2048]
    unsigned short* MT    = (unsigned short*)p; p += (size_t)Bb * Ddim * Ddim * 2; // [b][d2][d1]
    float* psum = (float*)p; p += (size_t)256 * Cdim * 4;
    float* psq  = (float*)p; p += (size_t)256 * Cdim * 4;
    float* avec = (float*)p; p += Cdim * 4;
    float* bvec = (float*)p; p += Cdim * 4;

    dim3 blk(256);

    // x_h -> bf16
    cast_x<<<6144, blk, 0, stream>>>(x_h, Xbuf, 1572864);
    cast_w<<<576, blk, 0, stream>>>(w_th, w_ph, w_g, w_out, Wth16, Wph16, Wg16, Wout16);
    // theta = x_h * w_theta^T + b_theta  (bf16 out, token-major)
    gemm_bf16<1><<<dim3(3, 128, 1), blk, 0, stream>>>(
        Xbuf, 0, Wth16, 0, b_th, Tbuf, 0, Mrows, Ddim, Cdim, 1.0f);
    // x_l -> bf16 (reuse Xbuf)
    cast_x<<<6144, blk, 0, stream>>>(x_l, Xbuf, 1572864);
    // phi  = x_l * w_phi^T + b_phi  -> transposed [b][d][n]
    gemm_bf16<2><<<dim3(3, 128, 1), blk, 0, stream>>>(
        Xbuf, 0, Wph16, 0, b_ph, PhiT, 0, Mrows, Ddim, Cdim, 1.0f);
    // g    = x_l * w_g^T + b_g     -> transposed [b][d][n]
    gemm_bf16<2><<<dim3(3, 128, 1), blk, 0, stream>>>(
        Xbuf, 0, Wg16, 0, b_g, GT, 0, Mrows, Ddim, Cdim, 1.0f);
    // MT[b][d2][d1] = sum_n g[n][d2] phi[n][d1] / 2048   (NT: A=GT, B=PhiT, K=2048)
    gemm_bf16<1><<<dim3(3, 3, 8), blk, 0, stream>>>(
        GT, (long)Ddim * Ntok, PhiT, (long)Ddim * Ntok, nullptr,
        MT, (long)Ddim * Ddim, Ddim, Ddim, Ntok, 1.0f / (float)Ntok);
    // y1 = theta * M  (NT: B=MT)  -> Y1 (reuses Xbuf)
    unsigned short* Y1 = Xbuf;
    gemm_bf16<1><<<dim3(3, 16, 8), blk, 0, stream>>>(
        Tbuf, (long)Ntok * Ddim, MT, (long)Ddim * Ddim, nullptr,
        Y1, (long)Ntok * Ddim, Ntok, Ddim, Ddim, 1.0f);
    // y = y1 * w_out^T + b_out -> fp32 d_out (pre-BN)
    gemm_bf16<0><<<dim3(6, 128, 1), blk, 0, stream>>>(
        Y1, 0, Wout16, 0, b_out, out, 0, Mrows, Cdim, Ddim, 1.0f);
    // BN stats + apply + residual
    bn_partial<<<dim3(Mrows / 64), blk, 0, stream>>>(out, psum, psq);
    bn_finalize<<<dim3(3), blk, 0, stream>>>(psum, psq, gamma, beta, avec, bvec);
    bn_apply<<<dim3((size_t)Mrows * Cdim / 4 / 256), blk, 0, stream>>>(
        out, x_h, avec, bvec, out);
}

// Round 5
// 196.403 us; speedup vs baseline: 4.2978x; 1.2171x over previous
//
#include <hip/hip_runtime.h>
#include <hip/hip_bf16.h>

typedef short bf16x8 __attribute__((ext_vector_type(8)));
typedef float f32x4 __attribute__((ext_vector_type(4)));

constexpr int Bb = 8, Ntok = 2048, Cdim = 768, Ddim = 384, Mrows = 16384;

__device__ __forceinline__ void gload16(const void* g, void* l) {
    __builtin_amdgcn_global_load_lds(
        (const __attribute__((address_space(1))) unsigned int*)g,
        (__attribute__((address_space(3))) unsigned int*)l, 16, 0, 0);
}

// Hand-rolled RNE fp32->bf16 (finite inputs only)
__device__ __forceinline__ unsigned short f2bf(float x) {
    union { float f; unsigned u; } c; c.f = x;
    const unsigned r = c.u + 0x7fffu + ((c.u >> 16) & 1u);
    return (unsigned short)(r >> 16);
}

// ---------------------------------------------------------------------------
// fp32 -> bf16 casts
// ---------------------------------------------------------------------------
__global__ __launch_bounds__(256) void cast_x(const float* __restrict__ s,
                                              unsigned short* __restrict__ d, int n8) {
    const int i = blockIdx.x * 256 + threadIdx.x;
    if (i >= n8) return;
    const float4* s4 = (const float4*)s;
    const float4 a = s4[2 * i], b = s4[2 * i + 1];
    union { unsigned short u[8]; uint4 q; } r;
    r.u[0] = f2bf(a.x); r.u[1] = f2bf(a.y); r.u[2] = f2bf(a.z); r.u[3] = f2bf(a.w);
    r.u[4] = f2bf(b.x); r.u[5] = f2bf(b.y); r.u[6] = f2bf(b.z); r.u[7] = f2bf(b.w);
    ((uint4*)d)[i] = r.q;
}

__global__ __launch_bounds__(256) void cast_w(const float* __restrict__ s0, const float* __restrict__ s1,
                                              const float* __restrict__ s2, const float* __restrict__ s3,
                                              unsigned short* __restrict__ d0, unsigned short* __restrict__ d1,
                                              unsigned short* __restrict__ d2, unsigned short* __restrict__ d3) {
    constexpr int n8 = 294912 / 8;  // 36864 uint4-chunks per weight
    const int i = blockIdx.x * 256 + threadIdx.x;  // 0..147455
    const int sel = i / n8, loc = i - sel * n8;
    const float* s = sel == 0 ? s0 : sel == 1 ? s1 : sel == 2 ? s2 : s3;
    unsigned short* d = sel == 0 ? d0 : sel == 1 ? d1 : sel == 2 ? d2 : d3;
    const float4* s4 = (const float4*)s;
    const float4 a = s4[2 * loc], b = s4[2 * loc + 1];
    union { unsigned short u[8]; uint4 q; } r;
    r.u[0] = f2bf(a.x); r.u[1] = f2bf(a.y); r.u[2] = f2bf(a.z); r.u[3] = f2bf(a.w);
    r.u[4] = f2bf(b.x); r.u[5] = f2bf(b.y); r.u[6] = f2bf(b.z); r.u[7] = f2bf(b.w);
    ((uint4*)d)[loc] = r.q;
}

// ---------------------------------------------------------------------------
// bf16 MFMA NT GEMM, 128x128 tile, BK=32, 4 waves (2x2), 64x64/wave,
// mfma_f32_16x16x32_bf16, global_load_lds w16, DOUBLE-BUFFERED (2-phase,
// counted vmcnt(4) — T3 minimum recipe).
// OMODE 0: fp32 out [M][N] (+bias if non-null)
// OMODE 1: bf16 out [M][N], optional bias, scale
// OMODE 2: bf16 out TRANSPOSED per batch: out[b][col][token] (+bias split)
// SPLITK : z = b*4+ks, K-slice = K/4, C indexed by z (fp32 partials)
// bias lookup: gcol < Nsplit ? bias[gcol] : bias2[gcol-Nsplit]
// ---------------------------------------------------------------------------
template <int OMODE, bool SPLITK>
__global__ __launch_bounds__(256) void gemm_bf16(
        const unsigned short* __restrict__ Abase, long sA,
        const unsigned short* __restrict__ Bbase, long sB,
        const float* __restrict__ bias, const float* __restrict__ bias2, int Nsplit,
        void* __restrict__ Cbase, long sC,
        int M, int N, int K, float scale) {
    constexpr int SMEM_BYTES = (OMODE == 2) ? 34304 : 32768;  // 2 bufs of 16K (A8K|B8K)
    __shared__ __align__(16) char smem[SMEM_BYTES];

    const int tid  = threadIdx.x;
    const int lane = tid & 63;
    const int w    = tid >> 6;
    const int wm   = w >> 1, wn = w & 1;
    const int bm = blockIdx.y * 128, bn = blockIdx.x * 128;
    const int zz = blockIdx.z;

    int zb, kStart, kEnd;
    if constexpr (SPLITK) {
        zb = zz >> 2;
        const int kl = K >> 2;
        kStart = (zz & 3) * kl;
        kEnd = kStart + kl;
    } else {
        zb = zz; kStart = 0; kEnd = K;
    }

    const unsigned short* A = Abase + (size_t)zb * sA;
    const unsigned short* B = Bbase + (size_t)zb * sB;

    // staging map: thread t covers 16B = 8 bf16 at tile (row=t>>2 (+64), k=(t&3)*8)
    const int ldRow = tid >> 2;
    const int ldK   = (tid & 3) * 8;
    const unsigned ldsOff = tid * 16;
    const size_t aOff0 = (size_t)(bm + ldRow) * K + ldK;
    const size_t aOff1 = (size_t)(bm + 64 + ldRow) * K + ldK;
    const size_t bOff0 = (size_t)(bn + ldRow) * K + ldK;
    const size_t bOff1 = (size_t)(bn + 64 + ldRow) * K + ldK;

    f32x4 acc[4][4] = {};

    const int fr = lane & 15;          // fragment row/col within 16
    const int fh = (lane >> 4) * 16;   // byte offset of k-octet

    auto STAGE = [&](int p, int k0) {
        char* s = smem + p * 16384;
        gload16(A + aOff0 + k0, s + ldsOff);
        gload16(A + aOff1 + k0, s + 4096 + ldsOff);
        gload16(B + bOff0 + k0, s + 8192 + ldsOff);
        gload16(B + bOff1 + k0, s + 12288 + ldsOff);
    };

    STAGE(0, kStart);
    int it = 0;
    for (int k0 = kStart; k0 < kEnd; k0 += 32, ++it) {
        const int p = it & 1;
        const bool more = (k0 + 32 < kEnd);
        if (more) {
            STAGE(p ^ 1, k0 + 32);  // issue next tile BEFORE consuming current
            asm volatile("s_waitcnt vmcnt(4)" ::: "memory");  // current 4 done, next 4 in flight
        } else {
            asm volatile("s_waitcnt vmcnt(0)" ::: "memory");
        }
        __syncthreads();
        const char* smA = smem + p * 16384;
        const char* smB = smA + 8192;
        bf16x8 fa[4], fb[4];
#pragma unroll
        for (int m = 0; m < 4; ++m)
            fa[m] = *(const bf16x8*)(smA + (wm * 64 + m * 16 + fr) * 64 + fh);
#pragma unroll
        for (int n = 0; n < 4; ++n)
            fb[n] = *(const bf16x8*)(smB + (wn * 64 + n * 16 + fr) * 64 + fh);
#pragma unroll
        for (int m = 0; m < 4; ++m)
#pragma unroll
            for (int n = 0; n < 4; ++n)
                acc[m][n] = __builtin_amdgcn_mfma_f32_16x16x32_bf16(fa[m], fb[n], acc[m][n], 0, 0, 0);
        __syncthreads();  // protect buf p from it+1's STAGE (which writes p)
    }

    const int r0 = (lane >> 4) * 4;
    const int cc = lane & 15;
    auto getbias = [&](int gcol) -> float {
        if (!bias) return 0.0f;
        return gcol < Nsplit ? bias[gcol] : bias2[gcol - Nsplit];
    };

    if constexpr (OMODE == 0) {
        float* C = (float*)Cbase + (size_t)(SPLITK ? zz : zb) * sC;
#pragma unroll
        for (int n = 0; n < 4; ++n) {
            const int col = bn + wn * 64 + n * 16 + cc;
            const float bv = getbias(col);
#pragma unroll
            for (int m = 0; m < 4; ++m)
#pragma unroll
                for (int j = 0; j < 4; ++j)
                    C[(size_t)(bm + wm * 64 + m * 16 + r0 + j) * N + col] = acc[m][n][j] + bv;
        }
    } else if constexpr (OMODE == 1) {
        unsigned short* C = (unsigned short*)Cbase + (size_t)zb * sC;
#pragma unroll
        for (int n = 0; n < 4; ++n) {
            const int col = bn + wn * 64 + n * 16 + cc;
            const float bv = getbias(col);
#pragma unroll
            for (int m = 0; m < 4; ++m)
#pragma unroll
                for (int j = 0; j < 4; ++j)
                    C[(size_t)(bm + wm * 64 + m * 16 + r0 + j) * N + col] =
                        f2bf(acc[m][n][j] * scale + bv);
        }
    } else {
        // OMODE 2: LDS transpose then coalesced store to [b][col][token]
        unsigned short* T = (unsigned short*)smem;  // [128 cols][134 rows] bf16 (pad 134)
#pragma unroll
        for (int n = 0; n < 4; ++n) {
            const int ccol = wn * 64 + n * 16 + cc;
            const float bv = getbias(bn + ccol);
#pragma unroll
            for (int m = 0; m < 4; ++m)
#pragma unroll
                for (int j = 0; j < 4; ++j)
                    T[ccol * 134 + (wm * 64 + m * 16 + r0 + j)] = f2bf(acc[m][n][j] + bv);
        }
        __syncthreads();
        const int b   = bm >> 11;     // bm / 2048 (Ntok = 2048)
        const int bmb = bm & 2047;
        unsigned short* Co = (unsigned short*)Cbase + (size_t)b * N * Ntok;
#pragma unroll
        for (int i = 0; i < 32; ++i) {
            const int d = w * 32 + i;  // column of tile, uniform per wave
            const unsigned v = *(const unsigned*)((const char*)smem + d * 268 + lane * 4);
            *(unsigned*)(Co + (size_t)(bn + d) * Ntok + bmb + lane * 2) = v;
        }
    }
}

// ---------------------------------------------------------------------------
// Split-K reduce: MT[b][i][j] = bf16( (1/2048) * sum_ks part[b*4+ks][i][j] )
// ---------------------------------------------------------------------------
__global__ __launch_bounds__(256) void reduce_mt(const float* __restrict__ part,
                                                 unsigned short* __restrict__ MTo) {
    const int i = blockIdx.x * 256 + threadIdx.x;   // float4 index; total 294912
    const int e = i * 4;
    const int b = e / (Ddim * Ddim);
    const int r = e - b * (Ddim * Ddim);
    const float* base = part + (size_t)b * 4 * (Ddim * Ddim) + r;
    float4 s = *(const float4*)(base);
    const float4 s1 = *(const float4*)(base + 1 * Ddim * Ddim);
    const float4 s2 = *(const float4*)(base + 2 * Ddim * Ddim);
    const float4 s3 = *(const float4*)(base + 3 * Ddim * Ddim);
    s.x += s1.x + s2.x + s3.x; s.y += s1.y + s2.y + s3.y;
    s.z += s1.z + s2.z + s3.z; s.w += s1.w + s2.w + s3.w;
    constexpr float sc = 1.0f / (float)Ntok;
    union { unsigned short u[4]; uint2 q; } o;
    o.u[0] = f2bf(s.x * sc); o.u[1] = f2bf(s.y * sc);
    o.u[2] = f2bf(s.z * sc); o.u[3] = f2bf(s.w * sc);
    *(uint2*)(MTo + e) = o.q;
}

// ---------------------------------------------------------------------------
// BN stats, deterministic two-stage column reduction over [16384][768]
// ---------------------------------------------------------------------------
__global__ __launch_bounds__(256) void bn_partial(const float* __restrict__ y,
                                                  float* __restrict__ psum,
                                                  float* __restrict__ psq) {
    const int tid = threadIdx.x;
    const size_t row0 = (size_t)blockIdx.x * 64;
    float s0 = 0, s1 = 0, s2 = 0, q0 = 0, q1 = 0, q2 = 0;
    for (int r = 0; r < 64; ++r) {
        const float* rp = y + (row0 + r) * Cdim;
        const float v0 = rp[tid];
        const float v1 = rp[tid + 256];
        const float v2 = rp[tid + 512];
        s0 += v0; q0 = fmaf(v0, v0, q0);
        s1 += v1; q1 = fmaf(v1, v1, q1);
        s2 += v2; q2 = fmaf(v2, v2, q2);
    }
    const size_t o = (size_t)blockIdx.x * Cdim;
    psum[o + tid] = s0; psum[o + tid + 256] = s1; psum[o + tid + 512] = s2;
    psq[o + tid]  = q0; psq[o + tid + 256]  = q1; psq[o + tid + 512]  = q2;
}

__global__ __launch_bounds__(256) void bn_finalize(const float* __restrict__ psum,
                                                   const float* __restrict__ psq,
                                                   const float* __restrict__ gamma,
                                                   const float* __restrict__ beta,
                                                   float* __restrict__ a,
                                                   float* __restrict__ bb) {
    const int c = blockIdx.x * 256 + threadIdx.x;
    if (c >= Cdim) return;
    float s = 0.f, q = 0.f;
    for (int b = 0; b < 256; ++b) { s += psum[(size_t)b * Cdim + c]; q += psq[(size_t)b * Cdim + c]; }
    const float mean = s * (1.0f / (float)Mrows);
    const float var  = fmaf(-mean, mean, q * (1.0f / (float)Mrows));
    const float inv  = rsqrtf(var + 1e-5f);
    const float gsc  = gamma[c] * inv;
    a[c]  = gsc;
    bb[c] = fmaf(-mean, gsc, beta[c]);
}

__global__ __launch_bounds__(256) void bn_apply(const float* __restrict__ y,
                                                const float* __restrict__ xh,
                                                const float* __restrict__ a,
                                                const float* __restrict__ bb,
                                                float* __restrict__ outp) {
    const size_t i = (size_t)blockIdx.x * 256 + threadIdx.x;  // float4 index
    const float4 v = ((const float4*)y)[i];
    const float4 x = ((const float4*)xh)[i];
    const int c4 = (int)(i % (Cdim / 4));
    const float4 A  = ((const float4*)a)[c4];
    const float4 Bv = ((const float4*)bb)[c4];
    float4 o;
    o.x = fmaf(A.x, v.x, Bv.x) + x.x;
    o.y = fmaf(A.y, v.y, Bv.y) + x.y;
    o.z = fmaf(A.z, v.z, Bv.z) + x.z;
    o.w = fmaf(A.w, v.w, Bv.w) + x.w;
    ((float4*)outp)[i] = o;
}

// ---------------------------------------------------------------------------
extern "C" void kernel_launch(void* const* d_in, const int* in_sizes, int n_in,
                              void* d_out, int out_size, void* d_ws, size_t ws_size,
                              hipStream_t stream) {
    const float* x_h   = (const float*)d_in[0];
    const float* x_l   = (const float*)d_in[1];
    const float* w_g   = (const float*)d_in[2];
    const float* b_g   = (const float*)d_in[3];
    const float* w_th  = (const float*)d_in[4];
    const float* b_th  = (const float*)d_in[5];
    const float* w_ph  = (const float*)d_in[6];
    const float* b_ph  = (const float*)d_in[7];
    const float* w_out = (const float*)d_in[8];
    const float* b_out = (const float*)d_in[9];
    const float* gamma = (const float*)d_in[10];
    const float* beta  = (const float*)d_in[11];
    float* out = (float*)d_out;

    // workspace layout (bytes, 16B aligned): ~69.5 MB
    char* p = (char*)d_ws;
    unsigned short* Xbuf  = (unsigned short*)p; p += (size_t)Mrows * Cdim * 2;  // 25.2MB: x bf16; later MT partials (18.9MB); later Y1 (12.6MB)
    unsigned short* Wth16 = (unsigned short*)p; p += 294912 * 2;
    unsigned short* Wpg16 = (unsigned short*)p; p += 2 * 294912 * 2;            // [768][768]: rows 0-383 w_phi, 384-767 w_g
    unsigned short* Wout16= (unsigned short*)p; p += 294912 * 2;
    unsigned short* Tbuf  = (unsigned short*)p; p += (size_t)Mrows * Ddim * 2;  // theta bf16
    unsigned short* PGT   = (unsigned short*)p; p += (size_t)Mrows * Cdim * 2;  // [b][768][2048]: rows 0-383 phi^T, 384-767 g^T
    unsigned short* MT    = (unsigned short*)p; p += (size_t)Bb * Ddim * Ddim * 2; // [b][d2][d1]
    float* psum = (float*)p; p += (size_t)256 * Cdim * 4;
    float* psq  = (float*)p; p += (size_t)256 * Cdim * 4;
    float* avec = (float*)p; p += Cdim * 4;
    float* bvec = (float*)p; p += Cdim * 4;
    float* part = (float*)Xbuf;  // split-K partials [32][384*384] fp32, alias (x_l dead by then)

    dim3 blk(256);
    const int BIG = 1 << 30;

    cast_x<<<6144, blk, 0, stream>>>(x_h, Xbuf, 1572864);
    cast_w<<<576, blk, 0, stream>>>(w_th, w_ph, w_g, w_out,
                                    Wth16, Wpg16, Wpg16 + 294912, Wout16);
    // theta = x_h * w_theta^T + b_theta (bf16 out, token-major)
    gemm_bf16<1, false><<<dim3(3, 128, 1), blk, 0, stream>>>(
        Xbuf, 0, Wth16, 0, b_th, nullptr, BIG, Tbuf, 0, Mrows, Ddim, Cdim, 1.0f);
    // x_l -> bf16 (reuse Xbuf)
    cast_x<<<6144, blk, 0, stream>>>(x_l, Xbuf, 1572864);
    // [phi | g] = x_l * [w_phi | w_g]^T + [b_phi | b_g] -> transposed [b][768][2048]
    gemm_bf16<2, false><<<dim3(6, 128, 1), blk, 0, stream>>>(
        Xbuf, 0, Wpg16, 0, b_ph, b_g, Ddim, PGT, 0, Mrows, 2 * Ddim, Cdim, 1.0f);
    // MT partials: part[b*4+ks][d2][d1] = sum_{n in slice} g^T[d2][n] * phi^T[d1][n]
    gemm_bf16<0, true><<<dim3(3, 3, 32), blk, 0, stream>>>(
        PGT + (size_t)Ddim * Ntok, (long)2 * Ddim * Ntok,
        PGT, (long)2 * Ddim * Ntok, nullptr, nullptr, BIG,
        part, (long)Ddim * Ddim, Ddim, Ddim, Ntok, 1.0f);
    reduce_mt<<<1152, blk, 0, stream>>>(part, MT);
    // y1 = theta * M (NT: B=MT) -> Y1 (reuses Xbuf; partials consumed)
    unsigned short* Y1 = Xbuf;
    gemm_bf16<1, false><<<dim3(3, 16, 8), blk, 0, stream>>>(
        Tbuf, (long)Ntok * Ddim, MT, (long)Ddim * Ddim, nullptr, nullptr, BIG,
        Y1, (long)Ntok * Ddim, Ntok, Ddim, Ddim, 1.0f);
    // y = y1 * w_out^T + b_out -> fp32 d_out (pre-BN)
    gemm_bf16<0, false><<<dim3(6, 128, 1), blk, 0, stream>>>(
        Y1, 0, Wout16, 0, b_out, nullptr, BIG, out, 0, Mrows, Cdim, Ddim, 1.0f);
    // BN stats + apply + residual
    bn_partial<<<dim3(Mrows / 64), blk, 0, stream>>>(out, psum, psq);
    bn_finalize<<<dim3(3), blk, 0, stream>>>(psum, psq, gamma, beta, avec, bvec);
    bn_apply<<<dim3((size_t)Mrows * Cdim / 4 / 256), blk, 0, stream>>>(
        out, x_h, avec, bvec, out);
}

// Round 6
// 174.105 us; speedup vs baseline: 4.8482x; 1.1281x over previous
//
#include <hip/hip_runtime.h>
#include <hip/hip_bf16.h>

typedef short bf16x8 __attribute__((ext_vector_type(8)));
typedef float f32x4 __attribute__((ext_vector_type(4)));

constexpr int Bb = 8, Ntok = 2048, Cdim = 768, Ddim = 384, Mrows = 16384;

__device__ __forceinline__ void gload16(const void* g, void* l) {
    __builtin_amdgcn_global_load_lds(
        (const __attribute__((address_space(1))) unsigned int*)g,
        (__attribute__((address_space(3))) unsigned int*)l, 16, 0, 0);
}

// Hand-rolled RNE fp32->bf16 (finite inputs only)
__device__ __forceinline__ unsigned short f2bf(float x) {
    union { float f; unsigned u; } c; c.f = x;
    const unsigned r = c.u + 0x7fffu + ((c.u >> 16) & 1u);
    return (unsigned short)(r >> 16);
}
__device__ __forceinline__ float bf2f(unsigned short u) {
    union { unsigned u; float f; } c; c.u = (unsigned)u << 16;
    return c.f;
}

// ---------------------------------------------------------------------------
// fp32 -> bf16 casts
// ---------------------------------------------------------------------------
__global__ __launch_bounds__(256) void cast_x(const float* __restrict__ s,
                                              unsigned short* __restrict__ d, int n8) {
    const int i = blockIdx.x * 256 + threadIdx.x;
    if (i >= n8) return;
    const float4* s4 = (const float4*)s;
    const float4 a = s4[2 * i], b = s4[2 * i + 1];
    union { unsigned short u[8]; uint4 q; } r;
    r.u[0] = f2bf(a.x); r.u[1] = f2bf(a.y); r.u[2] = f2bf(a.z); r.u[3] = f2bf(a.w);
    r.u[4] = f2bf(b.x); r.u[5] = f2bf(b.y); r.u[6] = f2bf(b.z); r.u[7] = f2bf(b.w);
    ((uint4*)d)[i] = r.q;
}

__global__ __launch_bounds__(256) void cast_w(const float* __restrict__ s0, const float* __restrict__ s1,
                                              const float* __restrict__ s2, const float* __restrict__ s3,
                                              unsigned short* __restrict__ d0, unsigned short* __restrict__ d1,
                                              unsigned short* __restrict__ d2, unsigned short* __restrict__ d3) {
    constexpr int n8 = 294912 / 8;
    const int i = blockIdx.x * 256 + threadIdx.x;
    const int sel = i / n8, loc = i - sel * n8;
    const float* s = sel == 0 ? s0 : sel == 1 ? s1 : sel == 2 ? s2 : s3;
    unsigned short* d = sel == 0 ? d0 : sel == 1 ? d1 : sel == 2 ? d2 : d3;
    const float4* s4 = (const float4*)s;
    const float4 a = s4[2 * loc], b = s4[2 * loc + 1];
    union { unsigned short u[8]; uint4 q; } r;
    r.u[0] = f2bf(a.x); r.u[1] = f2bf(a.y); r.u[2] = f2bf(a.z); r.u[3] = f2bf(a.w);
    r.u[4] = f2bf(b.x); r.u[5] = f2bf(b.y); r.u[6] = f2bf(b.z); r.u[7] = f2bf(b.w);
    ((uint4*)d)[loc] = r.q;
}

// ---------------------------------------------------------------------------
// bf16 MFMA NT GEMM, 128x128 tile, BK=32, 4 waves (2x2), 64x64/wave,
// mfma_f32_16x16x32_bf16, global_load_lds w16, double-buffered (counted vmcnt).
// OMODE 0: fp32 out [M][N] (+bias)
// OMODE 1: bf16 out [M][N] (+bias, scale)
// OMODE 2: bf16 out TRANSPOSED per batch: out[b][col][token] (+split bias)
// OMODE 3: bf16 out [M][N] + bias + fused BN column partial stats (fp32)
// SPLITK : z = zb*4+ks, K-slice = K/4, C indexed by z (fp32 partials)
// ---------------------------------------------------------------------------
template <int OMODE, bool SPLITK>
__global__ __launch_bounds__(256) void gemm_bf16(
        const unsigned short* __restrict__ Abase, long sA,
        const unsigned short* __restrict__ Bbase, long sB,
        const float* __restrict__ bias, const float* __restrict__ bias2, int Nsplit,
        void* __restrict__ Cbase, long sC,
        int M, int N, int K, float scale,
        float* __restrict__ psumG, float* __restrict__ psqG) {
    constexpr int SMEM_BYTES = (OMODE == 2) ? 34304 : 32768;
    __shared__ __align__(16) char smem[SMEM_BYTES];

    const int tid  = threadIdx.x;
    const int lane = tid & 63;
    const int w    = tid >> 6;
    const int wm   = w >> 1, wn = w & 1;
    const int bm = blockIdx.y * 128, bn = blockIdx.x * 128;
    const int zz = blockIdx.z;

    int zb, kStart, kEnd;
    if constexpr (SPLITK) {
        zb = zz >> 2;
        const int kl = K >> 2;
        kStart = (zz & 3) * kl;
        kEnd = kStart + kl;
    } else {
        zb = zz; kStart = 0; kEnd = K;
    }

    const unsigned short* A = Abase + (size_t)zb * sA;
    const unsigned short* B = Bbase + (size_t)zb * sB;

    const int ldRow = tid >> 2;
    const int ldK   = (tid & 3) * 8;
    const unsigned ldsOff = tid * 16;
    const size_t aOff0 = (size_t)(bm + ldRow) * K + ldK;
    const size_t aOff1 = (size_t)(bm + 64 + ldRow) * K + ldK;
    const size_t bOff0 = (size_t)(bn + ldRow) * K + ldK;
    const size_t bOff1 = (size_t)(bn + 64 + ldRow) * K + ldK;

    f32x4 acc[4][4] = {};

    const int fr = lane & 15;
    const int fh = (lane >> 4) * 16;

    auto STAGE = [&](int p, int k0) {
        char* s = smem + p * 16384;
        gload16(A + aOff0 + k0, s + ldsOff);
        gload16(A + aOff1 + k0, s + 4096 + ldsOff);
        gload16(B + bOff0 + k0, s + 8192 + ldsOff);
        gload16(B + bOff1 + k0, s + 12288 + ldsOff);
    };

    STAGE(0, kStart);
    int it = 0;
    for (int k0 = kStart; k0 < kEnd; k0 += 32, ++it) {
        const int p = it & 1;
        const bool more = (k0 + 32 < kEnd);
        if (more) {
            STAGE(p ^ 1, k0 + 32);
            asm volatile("s_waitcnt vmcnt(4)" ::: "memory");
        } else {
            asm volatile("s_waitcnt vmcnt(0)" ::: "memory");
        }
        __syncthreads();
        const char* smA = smem + p * 16384;
        const char* smB = smA + 8192;
        bf16x8 fa[4], fb[4];
#pragma unroll
        for (int m = 0; m < 4; ++m)
            fa[m] = *(const bf16x8*)(smA + (wm * 64 + m * 16 + fr) * 64 + fh);
#pragma unroll
        for (int n = 0; n < 4; ++n)
            fb[n] = *(const bf16x8*)(smB + (wn * 64 + n * 16 + fr) * 64 + fh);
#pragma unroll
        for (int m = 0; m < 4; ++m)
#pragma unroll
            for (int n = 0; n < 4; ++n)
                acc[m][n] = __builtin_amdgcn_mfma_f32_16x16x32_bf16(fa[m], fb[n], acc[m][n], 0, 0, 0);
        __syncthreads();
    }

    const int r0 = (lane >> 4) * 4;
    const int cc = lane & 15;
    auto getbias = [&](int gcol) -> float {
        if (!bias) return 0.0f;
        return gcol < Nsplit ? bias[gcol] : bias2[gcol - Nsplit];
    };

    if constexpr (OMODE == 0) {
        float* C = (float*)Cbase + (size_t)(SPLITK ? zz : zb) * sC;
#pragma unroll
        for (int n = 0; n < 4; ++n) {
            const int col = bn + wn * 64 + n * 16 + cc;
            const float bv = getbias(col);
#pragma unroll
            for (int m = 0; m < 4; ++m)
#pragma unroll
                for (int j = 0; j < 4; ++j)
                    C[(size_t)(bm + wm * 64 + m * 16 + r0 + j) * N + col] = acc[m][n][j] + bv;
        }
    } else if constexpr (OMODE == 1) {
        unsigned short* C = (unsigned short*)Cbase + (size_t)zb * sC;
#pragma unroll
        for (int n = 0; n < 4; ++n) {
            const int col = bn + wn * 64 + n * 16 + cc;
            const float bv = getbias(col);
#pragma unroll
            for (int m = 0; m < 4; ++m)
#pragma unroll
                for (int j = 0; j < 4; ++j)
                    C[(size_t)(bm + wm * 64 + m * 16 + r0 + j) * N + col] =
                        f2bf(acc[m][n][j] * scale + bv);
        }
    } else if constexpr (OMODE == 2) {
        // LDS transpose then coalesced store to [b][col][token]
        unsigned short* T = (unsigned short*)smem;  // [128 cols][134 rows] bf16
#pragma unroll
        for (int n = 0; n < 4; ++n) {
            const int ccol = wn * 64 + n * 16 + cc;
            const float bv = getbias(bn + ccol);
#pragma unroll
            for (int m = 0; m < 4; ++m)
#pragma unroll
                for (int j = 0; j < 4; ++j)
                    T[ccol * 134 + (wm * 64 + m * 16 + r0 + j)] = f2bf(acc[m][n][j] + bv);
        }
        __syncthreads();
        const int b   = bm >> 11;
        const int bmb = bm & 2047;
        unsigned short* Co = (unsigned short*)Cbase + (size_t)b * N * Ntok;
#pragma unroll
        for (int i = 0; i < 32; ++i) {
            const int d = w * 32 + i;
            const unsigned v = *(const unsigned*)((const char*)smem + d * 268 + lane * 4);
            *(unsigned*)(Co + (size_t)(bn + d) * Ntok + bmb + lane * 2) = v;
        }
    } else {
        // OMODE 3: bf16 out + deterministic per-block column stats
        unsigned short* C = (unsigned short*)Cbase + (size_t)zb * sC;
        float colS[4], colQ[4];
#pragma unroll
        for (int n = 0; n < 4; ++n) {
            const int col = bn + wn * 64 + n * 16 + cc;
            const float bv = getbias(col);
            float s = 0.f, q = 0.f;
#pragma unroll
            for (int m = 0; m < 4; ++m)
#pragma unroll
                for (int j = 0; j < 4; ++j) {
                    const float v = acc[m][n][j] + bv;
                    C[(size_t)(bm + wm * 64 + m * 16 + r0 + j) * N + col] = f2bf(v);
                    s += v; q = fmaf(v, v, q);
                }
            s += __shfl_xor(s, 16); s += __shfl_xor(s, 32);
            q += __shfl_xor(q, 16); q += __shfl_xor(q, 32);
            colS[n] = s; colQ[n] = q;
        }
        float* sums = (float*)smem;   // [2 wm][128 cols]
        float* sqs  = sums + 256;
        if (lane < 16) {
#pragma unroll
            for (int n = 0; n < 4; ++n) {
                sums[wm * 128 + wn * 64 + n * 16 + cc] = colS[n];
                sqs [wm * 128 + wn * 64 + n * 16 + cc] = colQ[n];
            }
        }
        __syncthreads();
        if (tid < 128) {
            const int slot = zb * gridDim.y + blockIdx.y;
            psumG[(size_t)slot * Cdim + bn + tid] = sums[tid] + sums[128 + tid];
            psqG [(size_t)slot * Cdim + bn + tid] = sqs[tid]  + sqs[128 + tid];
        }
    }
}

// ---------------------------------------------------------------------------
// Split-K reduce: M[b][d1][d2] = bf16( (1/2048) * sum_ks part[b*4+ks][d1][d2] )
// ---------------------------------------------------------------------------
__global__ __launch_bounds__(256) void reduce_mt(const float* __restrict__ part,
                                                 unsigned short* __restrict__ Mo) {
    const int i = blockIdx.x * 256 + threadIdx.x;   // float4 index; total 294912
    const int e = i * 4;
    const int b = e / (Ddim * Ddim);
    const int r = e - b * (Ddim * Ddim);
    const float* base = part + (size_t)b * 4 * (Ddim * Ddim) + r;
    float4 s = *(const float4*)(base);
    const float4 s1 = *(const float4*)(base + 1 * Ddim * Ddim);
    const float4 s2 = *(const float4*)(base + 2 * Ddim * Ddim);
    const float4 s3 = *(const float4*)(base + 3 * Ddim * Ddim);
    s.x += s1.x + s2.x + s3.x; s.y += s1.y + s2.y + s3.y;
    s.z += s1.z + s2.z + s3.z; s.w += s1.w + s2.w + s3.w;
    constexpr float sc = 1.0f / (float)Ntok;
    union { unsigned short u[4]; uint2 q; } o;
    o.u[0] = f2bf(s.x * sc); o.u[1] = f2bf(s.y * sc);
    o.u[2] = f2bf(s.z * sc); o.u[3] = f2bf(s.w * sc);
    *(uint2*)(Mo + e) = o.q;
}

// ---------------------------------------------------------------------------
// BN finalize: reduce 128 partial slots -> per-channel scale/shift
// ---------------------------------------------------------------------------
__global__ __launch_bounds__(256) void bn_finalize(const float* __restrict__ psum,
                                                   const float* __restrict__ psq,
                                                   const float* __restrict__ gamma,
                                                   const float* __restrict__ beta,
                                                   float* __restrict__ a,
                                                   float* __restrict__ bb) {
    const int c = blockIdx.x * 256 + threadIdx.x;
    if (c >= Cdim) return;
    float s = 0.f, q = 0.f;
    for (int b = 0; b < 128; ++b) { s += psum[(size_t)b * Cdim + c]; q += psq[(size_t)b * Cdim + c]; }
    const float mean = s * (1.0f / (float)Mrows);
    const float var  = fmaf(-mean, mean, q * (1.0f / (float)Mrows));
    const float inv  = rsqrtf(var + 1e-5f);
    const float gsc  = gamma[c] * inv;
    a[c]  = gsc;
    bb[c] = fmaf(-mean, gsc, beta[c]);
}

// out = a[c]*y + bb[c] + x_h ; y is bf16, out fp32
__global__ __launch_bounds__(256) void bn_apply(const unsigned short* __restrict__ y,
                                                const float* __restrict__ xh,
                                                const float* __restrict__ a,
                                                const float* __restrict__ bb,
                                                float* __restrict__ outp) {
    const size_t i = (size_t)blockIdx.x * 256 + threadIdx.x;  // uint4 index = 8 bf16
    union { uint4 q; unsigned short u[8]; } v; v.q = ((const uint4*)y)[i];
    const int c8 = (int)(i % (Cdim / 8));
    const float4 A0 = ((const float4*)a)[c8 * 2],  A1 = ((const float4*)a)[c8 * 2 + 1];
    const float4 B0 = ((const float4*)bb)[c8 * 2], B1 = ((const float4*)bb)[c8 * 2 + 1];
    const float4 X0 = ((const float4*)xh)[i * 2],  X1 = ((const float4*)xh)[i * 2 + 1];
    float4 o0, o1;
    o0.x = fmaf(A0.x, bf2f(v.u[0]), B0.x) + X0.x;
    o0.y = fmaf(A0.y, bf2f(v.u[1]), B0.y) + X0.y;
    o0.z = fmaf(A0.z, bf2f(v.u[2]), B0.z) + X0.z;
    o0.w = fmaf(A0.w, bf2f(v.u[3]), B0.w) + X0.w;
    o1.x = fmaf(A1.x, bf2f(v.u[4]), B1.x) + X1.x;
    o1.y = fmaf(A1.y, bf2f(v.u[5]), B1.y) + X1.y;
    o1.z = fmaf(A1.z, bf2f(v.u[6]), B1.z) + X1.z;
    o1.w = fmaf(A1.w, bf2f(v.u[7]), B1.w) + X1.w;
    ((float4*)outp)[i * 2]     = o0;
    ((float4*)outp)[i * 2 + 1] = o1;
}

// ---------------------------------------------------------------------------
extern "C" void kernel_launch(void* const* d_in, const int* in_sizes, int n_in,
                              void* d_out, int out_size, void* d_ws, size_t ws_size,
                              hipStream_t stream) {
    const float* x_h   = (const float*)d_in[0];
    const float* x_l   = (const float*)d_in[1];
    const float* w_g   = (const float*)d_in[2];
    const float* b_g   = (const float*)d_in[3];
    const float* w_th  = (const float*)d_in[4];
    const float* b_th  = (const float*)d_in[5];
    const float* w_ph  = (const float*)d_in[6];
    const float* b_ph  = (const float*)d_in[7];
    const float* w_out = (const float*)d_in[8];
    const float* b_out = (const float*)d_in[9];
    const float* gamma = (const float*)d_in[10];
    const float* beta  = (const float*)d_in[11];
    float* out = (float*)d_out;

    // workspace layout (~73 MB)
    char* p = (char*)d_ws;
    unsigned short* Xbuf  = (unsigned short*)p; p += (size_t)Mrows * Cdim * 2;  // 25.2MB: x bf16; then split-K partials (18.9MB); then Y bf16 (25.2MB)
    unsigned short* Wth16 = (unsigned short*)p; p += 294912 * 2;
    unsigned short* Wpg16 = (unsigned short*)p; p += 2 * 294912 * 2;            // [768][768]: rows 0-383 w_phi, 384-767 w_g
    unsigned short* Wout16= (unsigned short*)p; p += 294912 * 2;
    unsigned short* Tbuf  = (unsigned short*)p; p += (size_t)Mrows * Ddim * 2;  // theta bf16
    unsigned short* PGT   = (unsigned short*)p; p += (size_t)Mrows * Cdim * 2;  // [b][768][2048]: phi^T | g^T
    unsigned short* Mbuf  = (unsigned short*)p; p += (size_t)Bb * Ddim * Ddim * 2; // M[b][d1][d2]
    unsigned short* QTbuf = (unsigned short*)p; p += (size_t)Bb * Cdim * Ddim * 2; // QT[b][c][d1]
    float* psum = (float*)p; p += (size_t)128 * Cdim * 4;
    float* psq  = (float*)p; p += (size_t)128 * Cdim * 4;
    float* avec = (float*)p; p += Cdim * 4;
    float* bvec = (float*)p; p += Cdim * 4;
    float* part = (float*)Xbuf;              // split-K partials [32][384*384] fp32
    unsigned short* Ybuf = Xbuf;             // pre-BN y bf16 [16384][768]

    dim3 blk(256);
    const int BIG = 1 << 30;

    cast_x<<<6144, blk, 0, stream>>>(x_h, Xbuf, 1572864);
    cast_w<<<576, blk, 0, stream>>>(w_th, w_ph, w_g, w_out,
                                    Wth16, Wpg16, Wpg16 + 294912, Wout16);
    // theta = x_h * w_theta^T + b_theta (bf16, token-major)
    gemm_bf16<1, false><<<dim3(3, 128, 1), blk, 0, stream>>>(
        Xbuf, 0, Wth16, 0, b_th, nullptr, BIG, Tbuf, 0, Mrows, Ddim, Cdim, 1.0f,
        nullptr, nullptr);
    // x_l -> bf16 (reuse Xbuf)
    cast_x<<<6144, blk, 0, stream>>>(x_l, Xbuf, 1572864);
    // [phi | g] = x_l * [w_phi | w_g]^T + bias -> transposed [b][768][2048]
    gemm_bf16<2, false><<<dim3(6, 128, 1), blk, 0, stream>>>(
        Xbuf, 0, Wpg16, 0, b_ph, b_g, Ddim, PGT, 0, Mrows, 2 * Ddim, Cdim, 1.0f,
        nullptr, nullptr);
    // split-K partials: part[b*4+ks][d1][d2] = sum_{n slice} phi^T[d1][n] g^T[d2][n]
    gemm_bf16<0, true><<<dim3(3, 3, 32), blk, 0, stream>>>(
        PGT, (long)2 * Ddim * Ntok,
        PGT + (size_t)Ddim * Ntok, (long)2 * Ddim * Ntok, nullptr, nullptr, BIG,
        part, (long)Ddim * Ddim, Ddim, Ddim, Ntok, 1.0f, nullptr, nullptr);
    reduce_mt<<<1152, blk, 0, stream>>>(part, Mbuf);
    // QT[b][c][d1] = sum_d2 w_out[c][d2] * M[b][d1][d2]   (folds y1 away)
    gemm_bf16<1, false><<<dim3(3, 6, 8), blk, 0, stream>>>(
        Wout16, 0, Mbuf, (long)Ddim * Ddim, nullptr, nullptr, BIG,
        QTbuf, (long)Cdim * Ddim, Cdim, Ddim, Ddim, 1.0f, nullptr, nullptr);
    // y = theta * QT^T + b_out -> bf16 Ybuf, fused BN column partials
    gemm_bf16<3, false><<<dim3(6, 16, 8), blk, 0, stream>>>(
        Tbuf, (long)Ntok * Ddim, QTbuf, (long)Cdim * Ddim, b_out, nullptr, BIG,
        Ybuf, (long)Ntok * Cdim, Ntok, Cdim, Ddim, 1.0f, psum, psq);
    // BN finalize + apply + residual
    bn_finalize<<<dim3(3), blk, 0, stream>>>(psum, psq, gamma, beta, avec, bvec);
    bn_apply<<<dim3(6144), blk, 0, stream>>>(Ybuf, x_h, avec, bvec, out);
}